// Round 16
// baseline (62.752 us; speedup 1.0000x reference)
//
#include <hip/hip_runtime.h>
#include <math.h>

// OrthogonalButterfly: X (1024 x 8192) fp32, 20 butterfly layers, stride 2^(l%10).
// R15 = 31.6us plateau (scalar/pk path exhausted: all structural levers falsified).
// R16: MFMA path. 4 groups of 5 layers; each group = 32 independent 32x32
// orthogonal blocks (A-space: rows b*32..+31; B-space: rows == b mod 32).
// All boundaries are (site<->k) swaps. W[4][32] built on device, split
// W_hi + W_lo bf16 (2 chained MFMAs -> U error ~2^-17; X bf16 ~2^-9/stage).
// A/B fragment k-order self-consistent (any uniform k-permutation cancels in
// A.B); row/col = lane&15 and C/D map (col=l&15,row=(l>>4)*4+reg) m89-verified.
// Block: 512 thr, 32 cols, LDS 2x64KB bf16 tile buffers, grid 256, 4 barriers.
// Falls back to R15 tab/notab paths if ws_size < 512KB.

#define NROW   1024
#define BATCH  8192
#define BATCH2 (BATCH / 2)
#define DEPTH  20
#define NANG   512
#define TAB_ELEMS (DEPTH * NANG)
#define TAB_BYTES ((size_t)TAB_ELEMS * 8)
#define WS_MFMA_BYTES ((size_t)(4 * 32 * 1024) * 2 * 2)   // hi+lo, 512KB

typedef float v2f __attribute__((ext_vector_type(2)));
using bf16x8 = __attribute__((ext_vector_type(8))) short;
using f32x4  = __attribute__((ext_vector_type(4))) float;

__device__ __forceinline__ unsigned short f2b(float f) {
    union { float f; unsigned int u; } v; v.f = f;
    unsigned int u = v.u;
    return (unsigned short)((u + 0x7FFFu + ((u >> 16) & 1u)) >> 16);
}
__device__ __forceinline__ float b2f(unsigned short b) {
    union { unsigned int u; float f; } v; v.u = ((unsigned int)b) << 16;
    return v.f;
}

// ================= MFMA path =================
// W[grp][blk] 32x32 row-major: column j = 5 butterfly layers applied to e_j.
__global__ void build_w_kernel(const float* __restrict__ ang,
                               unsigned short* __restrict__ whi,
                               unsigned short* __restrict__ wlo) {
    int idx = blockIdx.x * blockDim.x + threadIdx.x;
    if (idx >= 4096) return;
    int grp = idx >> 10, b = (idx >> 5) & 31, j = idx & 31;
    float v[32];
    #pragma unroll
    for (int i = 0; i < 32; ++i) v[i] = (i == j) ? 1.f : 0.f;
    #pragma unroll
    for (int q = 0; q < 5; ++q) {
        int SL = 1 << q;
        int sp = (grp & 1) ? q + 5 : q;
        int l  = grp * 5 + q;
        int s  = 1 << sp;
        #pragma unroll
        for (int p = 0; p < 16; ++p) {
            int i0 = ((p >> q) << (q + 1)) | (p & (SL - 1));
            int i1 = i0 + SL;
            int r0 = (grp & 1) ? ((i0 << 5) | b) : ((b << 5) | i0);
            int a  = ((r0 >> (sp + 1)) << sp) | (r0 & (s - 1));
            float th = ang[l * NANG + a];
            float sv, cv; sincosf(th, &sv, &cv);
            float x0 = v[i0], x1 = v[i1];
            v[i0] = cv * x0 + sv * x1;
            v[i1] = cv * x1 - sv * x0;
        }
    }
    int mat = grp * 32 + b;
    #pragma unroll
    for (int i = 0; i < 32; ++i) {
        unsigned short h = f2b(v[i]);
        whi[mat * 1024 + i * 32 + j] = h;
        wlo[mat * 1024 + i * 32 + j] = f2b(v[i] - b2f(h));
    }
}

// Tile layout (bf16): ushort idx = site*512 + (k>>3)*128 + cc*16/2 + (k&7)
//   site = blk*2 + sigma (64 sites x 1KB = 64KB per buffer)
__global__ __launch_bounds__(512) void mfma_kernel(
        const float* __restrict__ X,
        const unsigned short* __restrict__ whi,
        const unsigned short* __restrict__ wlo,
        float* __restrict__ out) {
    __shared__ __align__(16) unsigned short sbuf[2][32768];   // 2 x 64KB
    int t  = threadIdx.x;
    int ln = t & 63;
    int w  = t >> 6;                          // wave id [0,8)
    int bid = blockIdx.x;
    int L = ((bid & 7) << 5) | (bid >> 3);    // XCD swizzle, bijective (256=8*32)
    int col0 = L << 5;                        // 32 cols per block

    // ---- entry: fp32 global -> bf16 tiles in buf0 ----
    {
        int cc = t & 15, sg = (t >> 4) & 1, bb = t >> 5;   // bb in [0,16)
        int col = col0 + sg * 16 + cc;
        #pragma unroll
        for (int half = 0; half < 2; ++half) {
            int rb = bb + 16 * half;
            int site = rb * 2 + sg;
            #pragma unroll
            for (int g = 0; g < 4; ++g) {
                unsigned int uu[4];
                #pragma unroll
                for (int jj = 0; jj < 4; ++jj) {
                    float va = X[(rb * 32 + g * 8 + 2 * jj) * BATCH + col];
                    float vb = X[(rb * 32 + g * 8 + 2 * jj + 1) * BATCH + col];
                    uu[jj] = (unsigned int)f2b(va) | ((unsigned int)f2b(vb) << 16);
                }
                *reinterpret_cast<uint4*>(&sbuf[0][site * 512 + g * 128 + cc * 8]) =
                    make_uint4(uu[0], uu[1], uu[2], uu[3]);
            }
        }
    }
    __syncthreads();

    const bf16x8* WH = reinterpret_cast<const bf16x8*>(whi);
    const bf16x8* WL = reinterpret_cast<const bf16x8*>(wlo);
    int r15 = ln & 15, kg = ln >> 4;

    #pragma unroll
    for (int grp = 0; grp < 4; ++grp) {
        int cur = grp & 1;
        #pragma unroll
        for (int m = 0; m < 4; ++m) {
            int rb  = (w & 7) + 8 * m;
            int mat = grp * 32 + rb;
            // A-frags: lane holds W[row=r15(+16)][k=kg*8..+7] (16B contiguous)
            bf16x8 ah0 = WH[mat * 128 + (r15     ) * 4 + kg];
            bf16x8 ah1 = WH[mat * 128 + (r15 + 16) * 4 + kg];
            bf16x8 al0 = WL[mat * 128 + (r15     ) * 4 + kg];
            bf16x8 al1 = WL[mat * 128 + (r15 + 16) * 4 + kg];
            #pragma unroll
            for (int sg2 = 0; sg2 < 2; ++sg2) {
                int site = rb * 2 + sg2;
                bf16x8 bf = *reinterpret_cast<const bf16x8*>(
                    &sbuf[cur][site * 512 + kg * 128 + r15 * 8]);
                f32x4 acc0 = {0.f, 0.f, 0.f, 0.f};
                f32x4 acc1 = {0.f, 0.f, 0.f, 0.f};
                acc0 = __builtin_amdgcn_mfma_f32_16x16x32_bf16(ah0, bf, acc0, 0, 0, 0);
                acc0 = __builtin_amdgcn_mfma_f32_16x16x32_bf16(al0, bf, acc0, 0, 0, 0);
                acc1 = __builtin_amdgcn_mfma_f32_16x16x32_bf16(ah1, bf, acc1, 0, 0, 0);
                acc1 = __builtin_amdgcn_mfma_f32_16x16x32_bf16(al1, bf, acc1, 0, 0, 0);
                if (grp < 3) {
                    // boundary: new site' = old_k*2+sigma, new k' = rb
                    #pragma unroll
                    for (int e = 0; e < 4; ++e) {
                        int k0 = kg * 4 + e;
                        int k1 = 16 + kg * 4 + e;
                        sbuf[cur ^ 1][(k0 * 2 + sg2) * 512 + (rb >> 3) * 128 +
                                      r15 * 8 + (rb & 7)] = f2b(acc0[e]);
                        sbuf[cur ^ 1][(k1 * 2 + sg2) * 512 + (rb >> 3) * 128 +
                                      r15 * 8 + (rb & 7)] = f2b(acc1[e]);
                    }
                } else {
                    // G3 is B-space: r = k*32 + class(rb); direct coalesced store
                    int col = col0 + sg2 * 16 + r15;
                    #pragma unroll
                    for (int e = 0; e < 4; ++e) {
                        int r0 = (kg * 4 + e) * 32 + rb;
                        int r1 = (16 + kg * 4 + e) * 32 + rb;
                        out[r0 * BATCH + col] = acc0[e];
                        out[r1 * BATCH + col] = acc1[e];
                    }
                }
            }
        }
        if (grp < 3) __syncthreads();
    }
}

// ================= fallback: R15 path (proven 31.6us) =================
__device__ __host__ __forceinline__ int rowA(int sub, int i){ return (sub << 5) | i; }
__device__ __host__ __forceinline__ int rowB(int sub, int i){ return sub | (i << 5); }

__global__ void build_tab_kernel(const float* __restrict__ ang,
                                 float2* __restrict__ tab) {
    int idx = blockIdx.x * blockDim.x + threadIdx.x;
    if (idx >= TAB_ELEMS) return;
    int l = idx >> 9;
    int slot = idx & (NANG - 1);
    int sub = slot >> 4, p = slot & 15;
    int m10 = l % 10;
    int sp = m10;
    int SL = 1 << (m10 % 5);
    int i0 = 2 * (p / SL) * SL + p % SL;
    int r = (m10 >= 5) ? rowB(sub, i0) : rowA(sub, i0);
    int a = ((r >> (sp + 1)) << sp) | (r & ((1 << sp) - 1));
    float th = ang[l * NANG + a];
    float sv, cv;
    sincosf(th, &sv, &cv);
    tab[idx] = make_float2(cv, sv);
}

__device__ __forceinline__ void rotp(v2f& a, v2f& b, float cv, float sv) {
    v2f c = {cv, cv}, s = {sv, sv};
    v2f x0 = a, x1 = b;
    a = __builtin_elementwise_fma(c, x0, s * x1);
    b = __builtin_elementwise_fma(-s, x0, c * x1);
}

template<int SL>
__device__ __forceinline__ void layer_tab(v2f y[32],
                                          const float4* __restrict__ q4) {
    #pragma unroll
    for (int v = 0; v < 8; ++v) {
        float4 q = q4[v];
        int p0 = 2 * v, p1 = 2 * v + 1;
        int a0 = 2 * (p0 / SL) * SL + p0 % SL;
        int a1 = 2 * (p1 / SL) * SL + p1 % SL;
        rotp(y[a0], y[a0 + SL], q.x, q.y);
        rotp(y[a1], y[a1 + SL], q.z, q.w);
    }
}

template<int SL, bool PB, int SP>
__device__ __forceinline__ void layer_notab(v2f y[32],
                                            const float* __restrict__ angL,
                                            int sub) {
    #pragma unroll
    for (int p = 0; p < 16; ++p) {
        int i0 = 2 * (p / SL) * SL + p % SL;
        int r = PB ? rowB(sub, i0) : rowA(sub, i0);
        int a = ((r >> (SP + 1)) << SP) | (r & ((1 << SP) - 1));
        float th = angL[a];
        float sv, cv;
        __sincosf(th, &sv, &cv);
        rotp(y[i0], y[i0 + SL], cv, sv);
    }
}

template<bool USE_TAB>
__global__ __launch_bounds__(256) void butterfly_kernel(
        const float* __restrict__ X, const float* __restrict__ ang,
        const float2* __restrict__ tab, float* __restrict__ out) {
    __shared__ v2f lds[8 * 1024];
    int t = threadIdx.x;
    int c = t & 7;
    int sub = t >> 3;
    int bid = blockIdx.x;
    int L = ((bid & 7) << 6) | (bid >> 3);
    int col2 = (L << 3) + c;
    int xr = (c & 7) << 1;
    v2f* base = lds + (c << 10);

    v2f y[32];
    const v2f* Xp = reinterpret_cast<const v2f*>(X) + col2;
    #pragma unroll
    for (int i = 0; i < 32; ++i)
        y[i] = Xp[rowA(sub, i) * BATCH2];

    const float4* tf4 = reinterpret_cast<const float4*>(tab);
    if (USE_TAB) {
        layer_tab<1 >(y, tf4 + 0 * 256 + 8 * sub);
        layer_tab<2 >(y, tf4 + 1 * 256 + 8 * sub);
        layer_tab<4 >(y, tf4 + 2 * 256 + 8 * sub);
        layer_tab<8 >(y, tf4 + 3 * 256 + 8 * sub);
        layer_tab<16>(y, tf4 + 4 * 256 + 8 * sub);
    } else {
        layer_notab<1 ,false,0>(y, ang + 0 * NANG, sub);
        layer_notab<2 ,false,1>(y, ang + 1 * NANG, sub);
        layer_notab<4 ,false,2>(y, ang + 2 * NANG, sub);
        layer_notab<8 ,false,3>(y, ang + 3 * NANG, sub);
        layer_notab<16,false,4>(y, ang + 4 * NANG, sub);
    }
    #pragma unroll
    for (int u = 0; u < 16; ++u)
        *reinterpret_cast<float4*>(&base[((sub << 5) + 2 * u) ^ xr]) =
            make_float4(y[2*u].x, y[2*u].y, y[2*u+1].x, y[2*u+1].y);
    __syncthreads();
    #pragma unroll
    for (int i = 0; i < 32; ++i) y[i] = base[rowB(sub, i) ^ xr];

    if (USE_TAB) {
        layer_tab<1 >(y, tf4 + 5 * 256 + 8 * sub);
        layer_tab<2 >(y, tf4 + 6 * 256 + 8 * sub);
        layer_tab<4 >(y, tf4 + 7 * 256 + 8 * sub);
        layer_tab<8 >(y, tf4 + 8 * 256 + 8 * sub);
        layer_tab<16>(y, tf4 + 9 * 256 + 8 * sub);
    } else {
        layer_notab<1 ,true,5>(y, ang + 5 * NANG, sub);
        layer_notab<2 ,true,6>(y, ang + 6 * NANG, sub);
        layer_notab<4 ,true,7>(y, ang + 7 * NANG, sub);
        layer_notab<8 ,true,8>(y, ang + 8 * NANG, sub);
        layer_notab<16,true,9>(y, ang + 9 * NANG, sub);
    }
    __syncthreads();
    #pragma unroll
    for (int i = 0; i < 32; ++i) base[rowB(sub, i) ^ xr] = y[i];
    __syncthreads();
    #pragma unroll
    for (int u = 0; u < 16; ++u) {
        float4 v = *reinterpret_cast<const float4*>(&base[((sub << 5) + 2 * u) ^ xr]);
        y[2*u].x = v.x; y[2*u].y = v.y; y[2*u+1].x = v.z; y[2*u+1].y = v.w;
    }

    if (USE_TAB) {
        layer_tab<1 >(y, tf4 + 10 * 256 + 8 * sub);
        layer_tab<2 >(y, tf4 + 11 * 256 + 8 * sub);
        layer_tab<4 >(y, tf4 + 12 * 256 + 8 * sub);
        layer_tab<8 >(y, tf4 + 13 * 256 + 8 * sub);
        layer_tab<16>(y, tf4 + 14 * 256 + 8 * sub);
    } else {
        layer_notab<1 ,false,0>(y, ang + 10 * NANG, sub);
        layer_notab<2 ,false,1>(y, ang + 11 * NANG, sub);
        layer_notab<4 ,false,2>(y, ang + 12 * NANG, sub);
        layer_notab<8 ,false,3>(y, ang + 13 * NANG, sub);
        layer_notab<16,false,4>(y, ang + 14 * NANG, sub);
    }
    __syncthreads();
    #pragma unroll
    for (int u = 0; u < 16; ++u)
        *reinterpret_cast<float4*>(&base[((sub << 5) + 2 * u) ^ xr]) =
            make_float4(y[2*u].x, y[2*u].y, y[2*u+1].x, y[2*u+1].y);
    __syncthreads();
    #pragma unroll
    for (int i = 0; i < 32; ++i) y[i] = base[rowB(sub, i) ^ xr];

    if (USE_TAB) {
        layer_tab<1 >(y, tf4 + 15 * 256 + 8 * sub);
        layer_tab<2 >(y, tf4 + 16 * 256 + 8 * sub);
        layer_tab<4 >(y, tf4 + 17 * 256 + 8 * sub);
        layer_tab<8 >(y, tf4 + 18 * 256 + 8 * sub);
        layer_tab<16>(y, tf4 + 19 * 256 + 8 * sub);
    } else {
        layer_notab<1 ,true,5>(y, ang + 15 * NANG, sub);
        layer_notab<2 ,true,6>(y, ang + 16 * NANG, sub);
        layer_notab<4 ,true,7>(y, ang + 17 * NANG, sub);
        layer_notab<8 ,true,8>(y, ang + 18 * NANG, sub);
        layer_notab<16,true,9>(y, ang + 19 * NANG, sub);
    }

    v2f* Op = reinterpret_cast<v2f*>(out) + col2;
    #pragma unroll
    for (int i = 0; i < 32; ++i)
        Op[rowB(sub, i) * BATCH2] = y[i];
}

extern "C" void kernel_launch(void* const* d_in, const int* in_sizes, int n_in,
                              void* d_out, int out_size, void* d_ws, size_t ws_size,
                              hipStream_t stream) {
    (void)in_sizes; (void)n_in; (void)out_size;
    const float* X   = (const float*)d_in[0];
    const float* ang = (const float*)d_in[1];
    float* out = (float*)d_out;

    if (d_ws != nullptr && ws_size >= WS_MFMA_BYTES) {
        unsigned short* whi = (unsigned short*)d_ws;
        unsigned short* wlo = whi + 4 * 32 * 1024;
        build_w_kernel<<<16, 256, 0, stream>>>(ang, whi, wlo);
        mfma_kernel<<<256, 512, 0, stream>>>(X, whi, wlo, out);
    } else if (d_ws != nullptr && ws_size >= TAB_BYTES) {
        float2* tab = (float2*)d_ws;
        build_tab_kernel<<<(TAB_ELEMS + 255) / 256, 256, 0, stream>>>(ang, tab);
        butterfly_kernel<true><<<512, 256, 0, stream>>>(X, ang, tab, out);
    } else {
        butterfly_kernel<false><<<512, 256, 0, stream>>>(X, ang, nullptr, out);
    }
}

// Round 17
// 44.809 us; speedup vs baseline: 1.4004x; 1.4004x over previous
//
#include <hip/hip_runtime.h>
#include <math.h>

// OrthogonalButterfly: X (1024 x 8192) fp32, 20 butterfly layers, stride 2^(l%10).
// R16: MFMA path passed (absmax 0.031 << 0.114) but build_w_kernel took 60-70us
// (16 blocks, precise sincosf x80/thread at near-zero occupancy).
// R17: builder fix only — __sincosf (hw v_sin/v_cos, error ~1e-6 << split-bf16
// 2^-17) and 64 blocks x 64 thr (one wave on each of 64 CUs). Main mfma_kernel
// byte-identical to R16 (proven correct).
// MFMA path: 4 groups of 5 layers; each group = 32 independent 32x32
// orthogonal blocks (A-space: rows b*32..+31; B-space: rows == b mod 32).
// Boundaries are (site<->k) swaps. W split W_hi+W_lo bf16, 2 chained MFMAs.
// Falls back to R15 tab/notab paths if ws_size < 512KB.

#define NROW   1024
#define BATCH  8192
#define BATCH2 (BATCH / 2)
#define DEPTH  20
#define NANG   512
#define TAB_ELEMS (DEPTH * NANG)
#define TAB_BYTES ((size_t)TAB_ELEMS * 8)
#define WS_MFMA_BYTES ((size_t)(4 * 32 * 1024) * 2 * 2)   // hi+lo, 512KB

typedef float v2f __attribute__((ext_vector_type(2)));
using bf16x8 = __attribute__((ext_vector_type(8))) short;
using f32x4  = __attribute__((ext_vector_type(4))) float;

__device__ __forceinline__ unsigned short f2b(float f) {
    union { float f; unsigned int u; } v; v.f = f;
    unsigned int u = v.u;
    return (unsigned short)((u + 0x7FFFu + ((u >> 16) & 1u)) >> 16);
}
__device__ __forceinline__ float b2f(unsigned short b) {
    union { unsigned int u; float f; } v; v.u = ((unsigned int)b) << 16;
    return v.f;
}

// ================= MFMA path =================
// W[grp][blk] 32x32 row-major: column j = 5 butterfly layers applied to e_j.
// R17: __sincosf + 64x64 launch (was precise sincosf at 16 blocks -> 60us).
__global__ void build_w_kernel(const float* __restrict__ ang,
                               unsigned short* __restrict__ whi,
                               unsigned short* __restrict__ wlo) {
    int idx = blockIdx.x * blockDim.x + threadIdx.x;
    if (idx >= 4096) return;
    int grp = idx >> 10, b = (idx >> 5) & 31, j = idx & 31;
    float v[32];
    #pragma unroll
    for (int i = 0; i < 32; ++i) v[i] = (i == j) ? 1.f : 0.f;
    #pragma unroll
    for (int q = 0; q < 5; ++q) {
        int SL = 1 << q;
        int sp = (grp & 1) ? q + 5 : q;
        int l  = grp * 5 + q;
        int s  = 1 << sp;
        #pragma unroll
        for (int p = 0; p < 16; ++p) {
            int i0 = ((p >> q) << (q + 1)) | (p & (SL - 1));
            int i1 = i0 + SL;
            int r0 = (grp & 1) ? ((i0 << 5) | b) : ((b << 5) | i0);
            int a  = ((r0 >> (sp + 1)) << sp) | (r0 & (s - 1));
            float th = ang[l * NANG + a];
            float sv, cv;
            __sincosf(th, &sv, &cv);
            float x0 = v[i0], x1 = v[i1];
            v[i0] = cv * x0 + sv * x1;
            v[i1] = cv * x1 - sv * x0;
        }
    }
    int mat = grp * 32 + b;
    #pragma unroll
    for (int i = 0; i < 32; ++i) {
        unsigned short h = f2b(v[i]);
        whi[mat * 1024 + i * 32 + j] = h;
        wlo[mat * 1024 + i * 32 + j] = f2b(v[i] - b2f(h));
    }
}

// Tile layout (bf16): ushort idx = site*512 + (k>>3)*128 + cc*8 + (k&7)
//   site = blk*2 + sigma (64 sites x 1KB = 64KB per buffer)
__global__ __launch_bounds__(512) void mfma_kernel(
        const float* __restrict__ X,
        const unsigned short* __restrict__ whi,
        const unsigned short* __restrict__ wlo,
        float* __restrict__ out) {
    __shared__ __align__(16) unsigned short sbuf[2][32768];   // 2 x 64KB
    int t  = threadIdx.x;
    int ln = t & 63;
    int w  = t >> 6;                          // wave id [0,8)
    int bid = blockIdx.x;
    int L = ((bid & 7) << 5) | (bid >> 3);    // XCD swizzle, bijective (256=8*32)
    int col0 = L << 5;                        // 32 cols per block

    // ---- entry: fp32 global -> bf16 tiles in buf0 ----
    {
        int cc = t & 15, sg = (t >> 4) & 1, bb = t >> 5;   // bb in [0,16)
        int col = col0 + sg * 16 + cc;
        #pragma unroll
        for (int half = 0; half < 2; ++half) {
            int rb = bb + 16 * half;
            int site = rb * 2 + sg;
            #pragma unroll
            for (int g = 0; g < 4; ++g) {
                unsigned int uu[4];
                #pragma unroll
                for (int jj = 0; jj < 4; ++jj) {
                    float va = X[(rb * 32 + g * 8 + 2 * jj) * BATCH + col];
                    float vb = X[(rb * 32 + g * 8 + 2 * jj + 1) * BATCH + col];
                    uu[jj] = (unsigned int)f2b(va) | ((unsigned int)f2b(vb) << 16);
                }
                *reinterpret_cast<uint4*>(&sbuf[0][site * 512 + g * 128 + cc * 8]) =
                    make_uint4(uu[0], uu[1], uu[2], uu[3]);
            }
        }
    }
    __syncthreads();

    const bf16x8* WH = reinterpret_cast<const bf16x8*>(whi);
    const bf16x8* WL = reinterpret_cast<const bf16x8*>(wlo);
    int r15 = ln & 15, kg = ln >> 4;

    #pragma unroll
    for (int grp = 0; grp < 4; ++grp) {
        int cur = grp & 1;
        #pragma unroll
        for (int m = 0; m < 4; ++m) {
            int rb  = (w & 7) + 8 * m;
            int mat = grp * 32 + rb;
            // A-frags: lane holds W[row=r15(+16)][k=kg*8..+7] (16B contiguous)
            bf16x8 ah0 = WH[mat * 128 + (r15     ) * 4 + kg];
            bf16x8 ah1 = WH[mat * 128 + (r15 + 16) * 4 + kg];
            bf16x8 al0 = WL[mat * 128 + (r15     ) * 4 + kg];
            bf16x8 al1 = WL[mat * 128 + (r15 + 16) * 4 + kg];
            #pragma unroll
            for (int sg2 = 0; sg2 < 2; ++sg2) {
                int site = rb * 2 + sg2;
                bf16x8 bf = *reinterpret_cast<const bf16x8*>(
                    &sbuf[cur][site * 512 + kg * 128 + r15 * 8]);
                f32x4 acc0 = {0.f, 0.f, 0.f, 0.f};
                f32x4 acc1 = {0.f, 0.f, 0.f, 0.f};
                acc0 = __builtin_amdgcn_mfma_f32_16x16x32_bf16(ah0, bf, acc0, 0, 0, 0);
                acc0 = __builtin_amdgcn_mfma_f32_16x16x32_bf16(al0, bf, acc0, 0, 0, 0);
                acc1 = __builtin_amdgcn_mfma_f32_16x16x32_bf16(ah1, bf, acc1, 0, 0, 0);
                acc1 = __builtin_amdgcn_mfma_f32_16x16x32_bf16(al1, bf, acc1, 0, 0, 0);
                if (grp < 3) {
                    // boundary: new site' = old_k*2+sigma, new k' = rb
                    #pragma unroll
                    for (int e = 0; e < 4; ++e) {
                        int k0 = kg * 4 + e;
                        int k1 = 16 + kg * 4 + e;
                        sbuf[cur ^ 1][(k0 * 2 + sg2) * 512 + (rb >> 3) * 128 +
                                      r15 * 8 + (rb & 7)] = f2b(acc0[e]);
                        sbuf[cur ^ 1][(k1 * 2 + sg2) * 512 + (rb >> 3) * 128 +
                                      r15 * 8 + (rb & 7)] = f2b(acc1[e]);
                    }
                } else {
                    // G3 is B-space: r = k*32 + class(rb); direct coalesced store
                    int col = col0 + sg2 * 16 + r15;
                    #pragma unroll
                    for (int e = 0; e < 4; ++e) {
                        int r0 = (kg * 4 + e) * 32 + rb;
                        int r1 = (16 + kg * 4 + e) * 32 + rb;
                        out[r0 * BATCH + col] = acc0[e];
                        out[r1 * BATCH + col] = acc1[e];
                    }
                }
            }
        }
        if (grp < 3) __syncthreads();
    }
}

// ================= fallback: R15 path (proven 31.6us) =================
__device__ __host__ __forceinline__ int rowA(int sub, int i){ return (sub << 5) | i; }
__device__ __host__ __forceinline__ int rowB(int sub, int i){ return sub | (i << 5); }

__global__ void build_tab_kernel(const float* __restrict__ ang,
                                 float2* __restrict__ tab) {
    int idx = blockIdx.x * blockDim.x + threadIdx.x;
    if (idx >= TAB_ELEMS) return;
    int l = idx >> 9;
    int slot = idx & (NANG - 1);
    int sub = slot >> 4, p = slot & 15;
    int m10 = l % 10;
    int sp = m10;
    int SL = 1 << (m10 % 5);
    int i0 = 2 * (p / SL) * SL + p % SL;
    int r = (m10 >= 5) ? rowB(sub, i0) : rowA(sub, i0);
    int a = ((r >> (sp + 1)) << sp) | (r & ((1 << sp) - 1));
    float th = ang[l * NANG + a];
    float sv, cv;
    sincosf(th, &sv, &cv);
    tab[idx] = make_float2(cv, sv);
}

__device__ __forceinline__ void rotp(v2f& a, v2f& b, float cv, float sv) {
    v2f c = {cv, cv}, s = {sv, sv};
    v2f x0 = a, x1 = b;
    a = __builtin_elementwise_fma(c, x0, s * x1);
    b = __builtin_elementwise_fma(-s, x0, c * x1);
}

template<int SL>
__device__ __forceinline__ void layer_tab(v2f y[32],
                                          const float4* __restrict__ q4) {
    #pragma unroll
    for (int v = 0; v < 8; ++v) {
        float4 q = q4[v];
        int p0 = 2 * v, p1 = 2 * v + 1;
        int a0 = 2 * (p0 / SL) * SL + p0 % SL;
        int a1 = 2 * (p1 / SL) * SL + p1 % SL;
        rotp(y[a0], y[a0 + SL], q.x, q.y);
        rotp(y[a1], y[a1 + SL], q.z, q.w);
    }
}

template<int SL, bool PB, int SP>
__device__ __forceinline__ void layer_notab(v2f y[32],
                                            const float* __restrict__ angL,
                                            int sub) {
    #pragma unroll
    for (int p = 0; p < 16; ++p) {
        int i0 = 2 * (p / SL) * SL + p % SL;
        int r = PB ? rowB(sub, i0) : rowA(sub, i0);
        int a = ((r >> (SP + 1)) << SP) | (r & ((1 << SP) - 1));
        float th = angL[a];
        float sv, cv;
        __sincosf(th, &sv, &cv);
        rotp(y[i0], y[i0 + SL], cv, sv);
    }
}

template<bool USE_TAB>
__global__ __launch_bounds__(256) void butterfly_kernel(
        const float* __restrict__ X, const float* __restrict__ ang,
        const float2* __restrict__ tab, float* __restrict__ out) {
    __shared__ v2f lds[8 * 1024];
    int t = threadIdx.x;
    int c = t & 7;
    int sub = t >> 3;
    int bid = blockIdx.x;
    int L = ((bid & 7) << 6) | (bid >> 3);
    int col2 = (L << 3) + c;
    int xr = (c & 7) << 1;
    v2f* base = lds + (c << 10);

    v2f y[32];
    const v2f* Xp = reinterpret_cast<const v2f*>(X) + col2;
    #pragma unroll
    for (int i = 0; i < 32; ++i)
        y[i] = Xp[rowA(sub, i) * BATCH2];

    const float4* tf4 = reinterpret_cast<const float4*>(tab);
    if (USE_TAB) {
        layer_tab<1 >(y, tf4 + 0 * 256 + 8 * sub);
        layer_tab<2 >(y, tf4 + 1 * 256 + 8 * sub);
        layer_tab<4 >(y, tf4 + 2 * 256 + 8 * sub);
        layer_tab<8 >(y, tf4 + 3 * 256 + 8 * sub);
        layer_tab<16>(y, tf4 + 4 * 256 + 8 * sub);
    } else {
        layer_notab<1 ,false,0>(y, ang + 0 * NANG, sub);
        layer_notab<2 ,false,1>(y, ang + 1 * NANG, sub);
        layer_notab<4 ,false,2>(y, ang + 2 * NANG, sub);
        layer_notab<8 ,false,3>(y, ang + 3 * NANG, sub);
        layer_notab<16,false,4>(y, ang + 4 * NANG, sub);
    }
    #pragma unroll
    for (int u = 0; u < 16; ++u)
        *reinterpret_cast<float4*>(&base[((sub << 5) + 2 * u) ^ xr]) =
            make_float4(y[2*u].x, y[2*u].y, y[2*u+1].x, y[2*u+1].y);
    __syncthreads();
    #pragma unroll
    for (int i = 0; i < 32; ++i) y[i] = base[rowB(sub, i) ^ xr];

    if (USE_TAB) {
        layer_tab<1 >(y, tf4 + 5 * 256 + 8 * sub);
        layer_tab<2 >(y, tf4 + 6 * 256 + 8 * sub);
        layer_tab<4 >(y, tf4 + 7 * 256 + 8 * sub);
        layer_tab<8 >(y, tf4 + 8 * 256 + 8 * sub);
        layer_tab<16>(y, tf4 + 9 * 256 + 8 * sub);
    } else {
        layer_notab<1 ,true,5>(y, ang + 5 * NANG, sub);
        layer_notab<2 ,true,6>(y, ang + 6 * NANG, sub);
        layer_notab<4 ,true,7>(y, ang + 7 * NANG, sub);
        layer_notab<8 ,true,8>(y, ang + 8 * NANG, sub);
        layer_notab<16,true,9>(y, ang + 9 * NANG, sub);
    }
    __syncthreads();
    #pragma unroll
    for (int i = 0; i < 32; ++i) base[rowB(sub, i) ^ xr] = y[i];
    __syncthreads();
    #pragma unroll
    for (int u = 0; u < 16; ++u) {
        float4 v = *reinterpret_cast<const float4*>(&base[((sub << 5) + 2 * u) ^ xr]);
        y[2*u].x = v.x; y[2*u].y = v.y; y[2*u+1].x = v.z; y[2*u+1].y = v.w;
    }

    if (USE_TAB) {
        layer_tab<1 >(y, tf4 + 10 * 256 + 8 * sub);
        layer_tab<2 >(y, tf4 + 11 * 256 + 8 * sub);
        layer_tab<4 >(y, tf4 + 12 * 256 + 8 * sub);
        layer_tab<8 >(y, tf4 + 13 * 256 + 8 * sub);
        layer_tab<16>(y, tf4 + 14 * 256 + 8 * sub);
    } else {
        layer_notab<1 ,false,0>(y, ang + 10 * NANG, sub);
        layer_notab<2 ,false,1>(y, ang + 11 * NANG, sub);
        layer_notab<4 ,false,2>(y, ang + 12 * NANG, sub);
        layer_notab<8 ,false,3>(y, ang + 13 * NANG, sub);
        layer_notab<16,false,4>(y, ang + 14 * NANG, sub);
    }
    __syncthreads();
    #pragma unroll
    for (int u = 0; u < 16; ++u)
        *reinterpret_cast<float4*>(&base[((sub << 5) + 2 * u) ^ xr]) =
            make_float4(y[2*u].x, y[2*u].y, y[2*u+1].x, y[2*u+1].y);
    __syncthreads();
    #pragma unroll
    for (int i = 0; i < 32; ++i) y[i] = base[rowB(sub, i) ^ xr];

    if (USE_TAB) {
        layer_tab<1 >(y, tf4 + 15 * 256 + 8 * sub);
        layer_tab<2 >(y, tf4 + 16 * 256 + 8 * sub);
        layer_tab<4 >(y, tf4 + 17 * 256 + 8 * sub);
        layer_tab<8 >(y, tf4 + 18 * 256 + 8 * sub);
        layer_tab<16>(y, tf4 + 19 * 256 + 8 * sub);
    } else {
        layer_notab<1 ,true,5>(y, ang + 15 * NANG, sub);
        layer_notab<2 ,true,6>(y, ang + 16 * NANG, sub);
        layer_notab<4 ,true,7>(y, ang + 17 * NANG, sub);
        layer_notab<8 ,true,8>(y, ang + 18 * NANG, sub);
        layer_notab<16,true,9>(y, ang + 19 * NANG, sub);
    }

    v2f* Op = reinterpret_cast<v2f*>(out) + col2;
    #pragma unroll
    for (int i = 0; i < 32; ++i)
        Op[rowB(sub, i) * BATCH2] = y[i];
}

extern "C" void kernel_launch(void* const* d_in, const int* in_sizes, int n_in,
                              void* d_out, int out_size, void* d_ws, size_t ws_size,
                              hipStream_t stream) {
    (void)in_sizes; (void)n_in; (void)out_size;
    const float* X   = (const float*)d_in[0];
    const float* ang = (const float*)d_in[1];
    float* out = (float*)d_out;

    if (d_ws != nullptr && ws_size >= WS_MFMA_BYTES) {
        unsigned short* whi = (unsigned short*)d_ws;
        unsigned short* wlo = whi + 4 * 32 * 1024;
        build_w_kernel<<<64, 64, 0, stream>>>(ang, whi, wlo);
        mfma_kernel<<<256, 512, 0, stream>>>(X, whi, wlo, out);
    } else if (d_ws != nullptr && ws_size >= TAB_BYTES) {
        float2* tab = (float2*)d_ws;
        build_tab_kernel<<<(TAB_ELEMS + 255) / 256, 256, 0, stream>>>(ang, tab);
        butterfly_kernel<true><<<512, 256, 0, stream>>>(X, ang, tab, out);
    } else {
        butterfly_kernel<false><<<512, 256, 0, stream>>>(X, ang, nullptr, out);
    }
}

// Round 18
// 29.834 us; speedup vs baseline: 2.1034x; 1.5020x over previous
//
#include <hip/hip_runtime.h>
#include <math.h>

// OrthogonalButterfly: X (1024 x 8192) fp32, 20 butterfly layers, stride 2^(l%10).
// R16/R17 forensics: mfma_kernel ~5-8us (R16 graph total 62.8 with builder
// profiled 60-70 alone); builder still ~35-40us in R17 (32x redundant sincos
// + 80 scattered loads per thread, VGPR-starved chain).
// R18: builder v3 — one wave per TWO matrices (64 waves, grid 64x64):
//   phase 1: 64 lanes cooperatively sincos the 160 shared angles into LDS
//            (<=3 scattered loads/lane, computed ONCE per wave);
//   phase 2: lane (h,j) applies 80 rotations to basis column j reading (c,s)
//            as LDS broadcasts; coalesced b16 column stores.
// mfma_kernel byte-identical to R16/R17 (proven, absmax 0.031 << 0.114).
// Fallback: R15 tab/notab paths if ws_size < 512KB.

#define NROW   1024
#define BATCH  8192
#define BATCH2 (BATCH / 2)
#define DEPTH  20
#define NANG   512
#define TAB_ELEMS (DEPTH * NANG)
#define TAB_BYTES ((size_t)TAB_ELEMS * 8)
#define WS_MFMA_BYTES ((size_t)(4 * 32 * 1024) * 2 * 2)   // hi+lo, 512KB

typedef float v2f __attribute__((ext_vector_type(2)));
using bf16x8 = __attribute__((ext_vector_type(8))) short;
using f32x4  = __attribute__((ext_vector_type(4))) float;

__device__ __forceinline__ unsigned short f2b(float f) {
    union { float f; unsigned int u; } v; v.f = f;
    unsigned int u = v.u;
    return (unsigned short)((u + 0x7FFFu + ((u >> 16) & 1u)) >> 16);
}
__device__ __forceinline__ float b2f(unsigned short b) {
    union { unsigned int u; float f; } v; v.u = ((unsigned int)b) << 16;
    return v.f;
}

// ================= MFMA path =================
// W[grp][b] 32x32 row-major: column j = 5 butterfly layers applied to e_j.
// R18 builder: wave widx handles matrices (grp, bpair*2+{0,1}).
__global__ __launch_bounds__(64) void build_w_kernel(
        const float* __restrict__ ang,
        unsigned short* __restrict__ whi,
        unsigned short* __restrict__ wlo) {
    __shared__ float2 cs[160];           // [h*80 + q*16 + p]
    int ln = threadIdx.x;                // [0,64)
    int widx = blockIdx.x;               // [0,64)
    int grp = widx >> 4;                 // [0,4)
    int bpair = widx & 15;               // [0,16)

    // phase 1: cooperative sincos of the 160 shared angles
    #pragma unroll
    for (int rnd = 0; rnd < 3; ++rnd) {
        int tt = ln + rnd * 64;
        if (tt < 160) {
            int h = tt >= 80;
            int u = tt - h * 80;
            int q = u >> 4, p = u & 15;
            int b = bpair * 2 + h;
            int sp = (grp & 1) ? q + 5 : q;
            int l  = grp * 5 + q;
            int s  = 1 << sp;
            int SL = 1 << q;
            int i0 = ((p >> q) << (q + 1)) | (p & (SL - 1));
            int r0 = (grp & 1) ? ((i0 << 5) | b) : ((b << 5) | i0);
            int a  = ((r0 >> (sp + 1)) << sp) | (r0 & (s - 1));
            float th = ang[l * NANG + a];
            float sv, cv;
            __sincosf(th, &sv, &cv);
            cs[tt] = make_float2(cv, sv);
        }
    }
    __syncthreads();

    // phase 2: lane (h, j) builds column j of matrix (grp, bpair*2+h)
    int h = ln >> 5, j = ln & 31;
    int b = bpair * 2 + h;
    float v[32];
    #pragma unroll
    for (int i = 0; i < 32; ++i) v[i] = (i == j) ? 1.f : 0.f;
    #pragma unroll
    for (int q = 0; q < 5; ++q) {
        int SL = 1 << q;
        #pragma unroll
        for (int p = 0; p < 16; ++p) {
            int i0 = ((p >> q) << (q + 1)) | (p & (SL - 1));
            int i1 = i0 + SL;
            float2 q2 = cs[h * 80 + q * 16 + p];   // broadcast read
            float x0 = v[i0], x1 = v[i1];
            v[i0] = q2.x * x0 + q2.y * x1;
            v[i1] = q2.x * x1 - q2.y * x0;
        }
    }
    int mat = grp * 32 + b;
    #pragma unroll
    for (int i = 0; i < 32; ++i) {
        unsigned short hh = f2b(v[i]);
        whi[mat * 1024 + i * 32 + j] = hh;               // coalesced 64B/half
        wlo[mat * 1024 + i * 32 + j] = f2b(v[i] - b2f(hh));
    }
}

// Tile layout (bf16): ushort idx = site*512 + (k>>3)*128 + cc*8 + (k&7)
//   site = blk*2 + sigma (64 sites x 1KB = 64KB per buffer)
__global__ __launch_bounds__(512) void mfma_kernel(
        const float* __restrict__ X,
        const unsigned short* __restrict__ whi,
        const unsigned short* __restrict__ wlo,
        float* __restrict__ out) {
    __shared__ __align__(16) unsigned short sbuf[2][32768];   // 2 x 64KB
    int t  = threadIdx.x;
    int ln = t & 63;
    int w  = t >> 6;                          // wave id [0,8)
    int bid = blockIdx.x;
    int L = ((bid & 7) << 5) | (bid >> 3);    // XCD swizzle, bijective (256=8*32)
    int col0 = L << 5;                        // 32 cols per block

    // ---- entry: fp32 global -> bf16 tiles in buf0 ----
    {
        int cc = t & 15, sg = (t >> 4) & 1, bb = t >> 5;   // bb in [0,16)
        int col = col0 + sg * 16 + cc;
        #pragma unroll
        for (int half = 0; half < 2; ++half) {
            int rb = bb + 16 * half;
            int site = rb * 2 + sg;
            #pragma unroll
            for (int g = 0; g < 4; ++g) {
                unsigned int uu[4];
                #pragma unroll
                for (int jj = 0; jj < 4; ++jj) {
                    float va = X[(rb * 32 + g * 8 + 2 * jj) * BATCH + col];
                    float vb = X[(rb * 32 + g * 8 + 2 * jj + 1) * BATCH + col];
                    uu[jj] = (unsigned int)f2b(va) | ((unsigned int)f2b(vb) << 16);
                }
                *reinterpret_cast<uint4*>(&sbuf[0][site * 512 + g * 128 + cc * 8]) =
                    make_uint4(uu[0], uu[1], uu[2], uu[3]);
            }
        }
    }
    __syncthreads();

    const bf16x8* WH = reinterpret_cast<const bf16x8*>(whi);
    const bf16x8* WL = reinterpret_cast<const bf16x8*>(wlo);
    int r15 = ln & 15, kg = ln >> 4;

    #pragma unroll
    for (int grp = 0; grp < 4; ++grp) {
        int cur = grp & 1;
        #pragma unroll
        for (int m = 0; m < 4; ++m) {
            int rb  = (w & 7) + 8 * m;
            int mat = grp * 32 + rb;
            // A-frags: lane holds W[row=r15(+16)][k=kg*8..+7] (16B contiguous)
            bf16x8 ah0 = WH[mat * 128 + (r15     ) * 4 + kg];
            bf16x8 ah1 = WH[mat * 128 + (r15 + 16) * 4 + kg];
            bf16x8 al0 = WL[mat * 128 + (r15     ) * 4 + kg];
            bf16x8 al1 = WL[mat * 128 + (r15 + 16) * 4 + kg];
            #pragma unroll
            for (int sg2 = 0; sg2 < 2; ++sg2) {
                int site = rb * 2 + sg2;
                bf16x8 bf = *reinterpret_cast<const bf16x8*>(
                    &sbuf[cur][site * 512 + kg * 128 + r15 * 8]);
                f32x4 acc0 = {0.f, 0.f, 0.f, 0.f};
                f32x4 acc1 = {0.f, 0.f, 0.f, 0.f};
                acc0 = __builtin_amdgcn_mfma_f32_16x16x32_bf16(ah0, bf, acc0, 0, 0, 0);
                acc0 = __builtin_amdgcn_mfma_f32_16x16x32_bf16(al0, bf, acc0, 0, 0, 0);
                acc1 = __builtin_amdgcn_mfma_f32_16x16x32_bf16(ah1, bf, acc1, 0, 0, 0);
                acc1 = __builtin_amdgcn_mfma_f32_16x16x32_bf16(al1, bf, acc1, 0, 0, 0);
                if (grp < 3) {
                    // boundary: new site' = old_k*2+sigma, new k' = rb
                    #pragma unroll
                    for (int e = 0; e < 4; ++e) {
                        int k0 = kg * 4 + e;
                        int k1 = 16 + kg * 4 + e;
                        sbuf[cur ^ 1][(k0 * 2 + sg2) * 512 + (rb >> 3) * 128 +
                                      r15 * 8 + (rb & 7)] = f2b(acc0[e]);
                        sbuf[cur ^ 1][(k1 * 2 + sg2) * 512 + (rb >> 3) * 128 +
                                      r15 * 8 + (rb & 7)] = f2b(acc1[e]);
                    }
                } else {
                    // G3 is B-space: r = k*32 + class(rb); direct coalesced store
                    int col = col0 + sg2 * 16 + r15;
                    #pragma unroll
                    for (int e = 0; e < 4; ++e) {
                        int r0 = (kg * 4 + e) * 32 + rb;
                        int r1 = (16 + kg * 4 + e) * 32 + rb;
                        out[r0 * BATCH + col] = acc0[e];
                        out[r1 * BATCH + col] = acc1[e];
                    }
                }
            }
        }
        if (grp < 3) __syncthreads();
    }
}

// ================= fallback: R15 path (proven 31.6us) =================
__device__ __host__ __forceinline__ int rowA(int sub, int i){ return (sub << 5) | i; }
__device__ __host__ __forceinline__ int rowB(int sub, int i){ return sub | (i << 5); }

__global__ void build_tab_kernel(const float* __restrict__ ang,
                                 float2* __restrict__ tab) {
    int idx = blockIdx.x * blockDim.x + threadIdx.x;
    if (idx >= TAB_ELEMS) return;
    int l = idx >> 9;
    int slot = idx & (NANG - 1);
    int sub = slot >> 4, p = slot & 15;
    int m10 = l % 10;
    int sp = m10;
    int SL = 1 << (m10 % 5);
    int i0 = 2 * (p / SL) * SL + p % SL;
    int r = (m10 >= 5) ? rowB(sub, i0) : rowA(sub, i0);
    int a = ((r >> (sp + 1)) << sp) | (r & ((1 << sp) - 1));
    float th = ang[l * NANG + a];
    float sv, cv;
    sincosf(th, &sv, &cv);
    tab[idx] = make_float2(cv, sv);
}

__device__ __forceinline__ void rotp(v2f& a, v2f& b, float cv, float sv) {
    v2f c = {cv, cv}, s = {sv, sv};
    v2f x0 = a, x1 = b;
    a = __builtin_elementwise_fma(c, x0, s * x1);
    b = __builtin_elementwise_fma(-s, x0, c * x1);
}

template<int SL>
__device__ __forceinline__ void layer_tab(v2f y[32],
                                          const float4* __restrict__ q4) {
    #pragma unroll
    for (int v = 0; v < 8; ++v) {
        float4 q = q4[v];
        int p0 = 2 * v, p1 = 2 * v + 1;
        int a0 = 2 * (p0 / SL) * SL + p0 % SL;
        int a1 = 2 * (p1 / SL) * SL + p1 % SL;
        rotp(y[a0], y[a0 + SL], q.x, q.y);
        rotp(y[a1], y[a1 + SL], q.z, q.w);
    }
}

template<int SL, bool PB, int SP>
__device__ __forceinline__ void layer_notab(v2f y[32],
                                            const float* __restrict__ angL,
                                            int sub) {
    #pragma unroll
    for (int p = 0; p < 16; ++p) {
        int i0 = 2 * (p / SL) * SL + p % SL;
        int r = PB ? rowB(sub, i0) : rowA(sub, i0);
        int a = ((r >> (SP + 1)) << SP) | (r & ((1 << SP) - 1));
        float th = angL[a];
        float sv, cv;
        __sincosf(th, &sv, &cv);
        rotp(y[i0], y[i0 + SL], cv, sv);
    }
}

template<bool USE_TAB>
__global__ __launch_bounds__(256) void butterfly_kernel(
        const float* __restrict__ X, const float* __restrict__ ang,
        const float2* __restrict__ tab, float* __restrict__ out) {
    __shared__ v2f lds[8 * 1024];
    int t = threadIdx.x;
    int c = t & 7;
    int sub = t >> 3;
    int bid = blockIdx.x;
    int L = ((bid & 7) << 6) | (bid >> 3);
    int col2 = (L << 3) + c;
    int xr = (c & 7) << 1;
    v2f* base = lds + (c << 10);

    v2f y[32];
    const v2f* Xp = reinterpret_cast<const v2f*>(X) + col2;
    #pragma unroll
    for (int i = 0; i < 32; ++i)
        y[i] = Xp[rowA(sub, i) * BATCH2];

    const float4* tf4 = reinterpret_cast<const float4*>(tab);
    if (USE_TAB) {
        layer_tab<1 >(y, tf4 + 0 * 256 + 8 * sub);
        layer_tab<2 >(y, tf4 + 1 * 256 + 8 * sub);
        layer_tab<4 >(y, tf4 + 2 * 256 + 8 * sub);
        layer_tab<8 >(y, tf4 + 3 * 256 + 8 * sub);
        layer_tab<16>(y, tf4 + 4 * 256 + 8 * sub);
    } else {
        layer_notab<1 ,false,0>(y, ang + 0 * NANG, sub);
        layer_notab<2 ,false,1>(y, ang + 1 * NANG, sub);
        layer_notab<4 ,false,2>(y, ang + 2 * NANG, sub);
        layer_notab<8 ,false,3>(y, ang + 3 * NANG, sub);
        layer_notab<16,false,4>(y, ang + 4 * NANG, sub);
    }
    #pragma unroll
    for (int u = 0; u < 16; ++u)
        *reinterpret_cast<float4*>(&base[((sub << 5) + 2 * u) ^ xr]) =
            make_float4(y[2*u].x, y[2*u].y, y[2*u+1].x, y[2*u+1].y);
    __syncthreads();
    #pragma unroll
    for (int i = 0; i < 32; ++i) y[i] = base[rowB(sub, i) ^ xr];

    if (USE_TAB) {
        layer_tab<1 >(y, tf4 + 5 * 256 + 8 * sub);
        layer_tab<2 >(y, tf4 + 6 * 256 + 8 * sub);
        layer_tab<4 >(y, tf4 + 7 * 256 + 8 * sub);
        layer_tab<8 >(y, tf4 + 8 * 256 + 8 * sub);
        layer_tab<16>(y, tf4 + 9 * 256 + 8 * sub);
    } else {
        layer_notab<1 ,true,5>(y, ang + 5 * NANG, sub);
        layer_notab<2 ,true,6>(y, ang + 6 * NANG, sub);
        layer_notab<4 ,true,7>(y, ang + 7 * NANG, sub);
        layer_notab<8 ,true,8>(y, ang + 8 * NANG, sub);
        layer_notab<16,true,9>(y, ang + 9 * NANG, sub);
    }
    __syncthreads();
    #pragma unroll
    for (int i = 0; i < 32; ++i) base[rowB(sub, i) ^ xr] = y[i];
    __syncthreads();
    #pragma unroll
    for (int u = 0; u < 16; ++u) {
        float4 v = *reinterpret_cast<const float4*>(&base[((sub << 5) + 2 * u) ^ xr]);
        y[2*u].x = v.x; y[2*u].y = v.y; y[2*u+1].x = v.z; y[2*u+1].y = v.w;
    }

    if (USE_TAB) {
        layer_tab<1 >(y, tf4 + 10 * 256 + 8 * sub);
        layer_tab<2 >(y, tf4 + 11 * 256 + 8 * sub);
        layer_tab<4 >(y, tf4 + 12 * 256 + 8 * sub);
        layer_tab<8 >(y, tf4 + 13 * 256 + 8 * sub);
        layer_tab<16>(y, tf4 + 14 * 256 + 8 * sub);
    } else {
        layer_notab<1 ,false,0>(y, ang + 10 * NANG, sub);
        layer_notab<2 ,false,1>(y, ang + 11 * NANG, sub);
        layer_notab<4 ,false,2>(y, ang + 12 * NANG, sub);
        layer_notab<8 ,false,3>(y, ang + 13 * NANG, sub);
        layer_notab<16,false,4>(y, ang + 14 * NANG, sub);
    }
    __syncthreads();
    #pragma unroll
    for (int u = 0; u < 16; ++u)
        *reinterpret_cast<float4*>(&base[((sub << 5) + 2 * u) ^ xr]) =
            make_float4(y[2*u].x, y[2*u].y, y[2*u+1].x, y[2*u+1].y);
    __syncthreads();
    #pragma unroll
    for (int i = 0; i < 32; ++i) y[i] = base[rowB(sub, i) ^ xr];

    if (USE_TAB) {
        layer_tab<1 >(y, tf4 + 15 * 256 + 8 * sub);
        layer_tab<2 >(y, tf4 + 16 * 256 + 8 * sub);
        layer_tab<4 >(y, tf4 + 17 * 256 + 8 * sub);
        layer_tab<8 >(y, tf4 + 18 * 256 + 8 * sub);
        layer_tab<16>(y, tf4 + 19 * 256 + 8 * sub);
    } else {
        layer_notab<1 ,true,5>(y, ang + 15 * NANG, sub);
        layer_notab<2 ,true,6>(y, ang + 16 * NANG, sub);
        layer_notab<4 ,true,7>(y, ang + 17 * NANG, sub);
        layer_notab<8 ,true,8>(y, ang + 18 * NANG, sub);
        layer_notab<16,true,9>(y, ang + 19 * NANG, sub);
    }

    v2f* Op = reinterpret_cast<v2f*>(out) + col2;
    #pragma unroll
    for (int i = 0; i < 32; ++i)
        Op[rowB(sub, i) * BATCH2] = y[i];
}

extern "C" void kernel_launch(void* const* d_in, const int* in_sizes, int n_in,
                              void* d_out, int out_size, void* d_ws, size_t ws_size,
                              hipStream_t stream) {
    (void)in_sizes; (void)n_in; (void)out_size;
    const float* X   = (const float*)d_in[0];
    const float* ang = (const float*)d_in[1];
    float* out = (float*)d_out;

    if (d_ws != nullptr && ws_size >= WS_MFMA_BYTES) {
        unsigned short* whi = (unsigned short*)d_ws;
        unsigned short* wlo = whi + 4 * 32 * 1024;
        build_w_kernel<<<64, 64, 0, stream>>>(ang, whi, wlo);
        mfma_kernel<<<256, 512, 0, stream>>>(X, whi, wlo, out);
    } else if (d_ws != nullptr && ws_size >= TAB_BYTES) {
        float2* tab = (float2*)d_ws;
        build_tab_kernel<<<(TAB_ELEMS + 255) / 256, 256, 0, stream>>>(ang, tab);
        butterfly_kernel<true><<<512, 256, 0, stream>>>(X, ang, tab, out);
    } else {
        butterfly_kernel<false><<<512, 256, 0, stream>>>(X, ang, nullptr, out);
    }
}

// Round 19
// 29.460 us; speedup vs baseline: 2.1301x; 1.0127x over previous
//
#include <hip/hip_runtime.h>
#include <math.h>

// OrthogonalButterfly: X (1024 x 8192) fp32, 20 butterfly layers, stride 2^(l%10).
// R18 = 29.8us (MFMA path, absmax 0.031). mfma_kernel ~28us of it: 128KB LDS
// -> 1 block/CU -> serial chain; 192 b16 scatter writes w/ 8-way conflicts;
// 64 W-frag loads.
// R19: single 64KB LDS buffer. Per group: batched read of all 8 B-fragments
// (8x ds_read_b128 pipelined) -> barrier -> MFMA + scatter into SAME buffer
// -> barrier. 2 blocks/CU (launch_bounds(512,4) caps VGPR 128). Numerics and
// layouts byte-identical to R18.
// Fallback: R15 tab/notab paths if ws_size < 512KB.

#define NROW   1024
#define BATCH  8192
#define BATCH2 (BATCH / 2)
#define DEPTH  20
#define NANG   512
#define TAB_ELEMS (DEPTH * NANG)
#define TAB_BYTES ((size_t)TAB_ELEMS * 8)
#define WS_MFMA_BYTES ((size_t)(4 * 32 * 1024) * 2 * 2)   // hi+lo, 512KB

typedef float v2f __attribute__((ext_vector_type(2)));
using bf16x8 = __attribute__((ext_vector_type(8))) short;
using f32x4  = __attribute__((ext_vector_type(4))) float;

__device__ __forceinline__ unsigned short f2b(float f) {
    union { float f; unsigned int u; } v; v.f = f;
    unsigned int u = v.u;
    return (unsigned short)((u + 0x7FFFu + ((u >> 16) & 1u)) >> 16);
}
__device__ __forceinline__ float b2f(unsigned short b) {
    union { unsigned int u; float f; } v; v.u = ((unsigned int)b) << 16;
    return v.f;
}

// ================= MFMA path =================
// W[grp][b] 32x32 row-major: column j = 5 butterfly layers applied to e_j.
// R18 builder: wave widx handles matrices (grp, bpair*2+{0,1}).
__global__ __launch_bounds__(64) void build_w_kernel(
        const float* __restrict__ ang,
        unsigned short* __restrict__ whi,
        unsigned short* __restrict__ wlo) {
    __shared__ float2 cs[160];           // [h*80 + q*16 + p]
    int ln = threadIdx.x;                // [0,64)
    int widx = blockIdx.x;               // [0,64)
    int grp = widx >> 4;                 // [0,4)
    int bpair = widx & 15;               // [0,16)

    // phase 1: cooperative sincos of the 160 shared angles
    #pragma unroll
    for (int rnd = 0; rnd < 3; ++rnd) {
        int tt = ln + rnd * 64;
        if (tt < 160) {
            int h = tt >= 80;
            int u = tt - h * 80;
            int q = u >> 4, p = u & 15;
            int b = bpair * 2 + h;
            int sp = (grp & 1) ? q + 5 : q;
            int l  = grp * 5 + q;
            int s  = 1 << sp;
            int SL = 1 << q;
            int i0 = ((p >> q) << (q + 1)) | (p & (SL - 1));
            int r0 = (grp & 1) ? ((i0 << 5) | b) : ((b << 5) | i0);
            int a  = ((r0 >> (sp + 1)) << sp) | (r0 & (s - 1));
            float th = ang[l * NANG + a];
            float sv, cv;
            __sincosf(th, &sv, &cv);
            cs[tt] = make_float2(cv, sv);
        }
    }
    __syncthreads();

    // phase 2: lane (h, j) builds column j of matrix (grp, bpair*2+h)
    int h = ln >> 5, j = ln & 31;
    int b = bpair * 2 + h;
    float v[32];
    #pragma unroll
    for (int i = 0; i < 32; ++i) v[i] = (i == j) ? 1.f : 0.f;
    #pragma unroll
    for (int q = 0; q < 5; ++q) {
        int SL = 1 << q;
        #pragma unroll
        for (int p = 0; p < 16; ++p) {
            int i0 = ((p >> q) << (q + 1)) | (p & (SL - 1));
            int i1 = i0 + SL;
            float2 q2 = cs[h * 80 + q * 16 + p];   // broadcast read
            float x0 = v[i0], x1 = v[i1];
            v[i0] = q2.x * x0 + q2.y * x1;
            v[i1] = q2.x * x1 - q2.y * x0;
        }
    }
    int mat = grp * 32 + b;
    #pragma unroll
    for (int i = 0; i < 32; ++i) {
        unsigned short hh = f2b(v[i]);
        whi[mat * 1024 + i * 32 + j] = hh;               // coalesced 64B/half
        wlo[mat * 1024 + i * 32 + j] = f2b(v[i] - b2f(hh));
    }
}

// Tile layout (bf16): ushort idx = site*512 + (k>>3)*128 + cc*8 + (k&7)
//   site = blk*2 + sigma (64 sites x 1KB = 64KB, single buffer)
__global__ __launch_bounds__(512, 4) void mfma_kernel(
        const float* __restrict__ X,
        const unsigned short* __restrict__ whi,
        const unsigned short* __restrict__ wlo,
        float* __restrict__ out) {
    __shared__ __align__(16) unsigned short sbuf[32768];   // 64KB -> 2 blocks/CU
    int t  = threadIdx.x;
    int ln = t & 63;
    int w  = t >> 6;                          // wave id [0,8)
    int bid = blockIdx.x;
    int L = ((bid & 7) << 5) | (bid >> 3);    // XCD swizzle, bijective (256=8*32)
    int col0 = L << 5;                        // 32 cols per block

    // ---- entry: fp32 global -> bf16 tiles ----
    {
        int cc = t & 15, sg = (t >> 4) & 1, bb = t >> 5;   // bb in [0,16)
        int col = col0 + sg * 16 + cc;
        #pragma unroll
        for (int half = 0; half < 2; ++half) {
            int rb = bb + 16 * half;
            int site = rb * 2 + sg;
            #pragma unroll
            for (int g = 0; g < 4; ++g) {
                unsigned int uu[4];
                #pragma unroll
                for (int jj = 0; jj < 4; ++jj) {
                    float va = X[(rb * 32 + g * 8 + 2 * jj) * BATCH + col];
                    float vb = X[(rb * 32 + g * 8 + 2 * jj + 1) * BATCH + col];
                    uu[jj] = (unsigned int)f2b(va) | ((unsigned int)f2b(vb) << 16);
                }
                *reinterpret_cast<uint4*>(&sbuf[site * 512 + g * 128 + cc * 8]) =
                    make_uint4(uu[0], uu[1], uu[2], uu[3]);
            }
        }
    }
    __syncthreads();

    const bf16x8* WH = reinterpret_cast<const bf16x8*>(whi);
    const bf16x8* WL = reinterpret_cast<const bf16x8*>(wlo);
    int r15 = ln & 15, kg = ln >> 4;

    #pragma unroll
    for (int grp = 0; grp < 4; ++grp) {
        // ---- batched reads: all 8 B-fragments for this group ----
        bf16x8 bf[8];
        #pragma unroll
        for (int m = 0; m < 4; ++m) {
            int rb = (w & 7) + 8 * m;
            #pragma unroll
            for (int sg2 = 0; sg2 < 2; ++sg2) {
                int site = rb * 2 + sg2;
                bf[m * 2 + sg2] = *reinterpret_cast<const bf16x8*>(
                    &sbuf[site * 512 + kg * 128 + r15 * 8]);
            }
        }
        if (grp < 3) __syncthreads();    // all reads done before any write

        #pragma unroll
        for (int m = 0; m < 4; ++m) {
            int rb  = (w & 7) + 8 * m;
            int mat = grp * 32 + rb;
            // A-frags: lane holds W[row=r15(+16)][k=kg*8..+7] (16B contiguous)
            bf16x8 ah0 = WH[mat * 128 + (r15     ) * 4 + kg];
            bf16x8 ah1 = WH[mat * 128 + (r15 + 16) * 4 + kg];
            bf16x8 al0 = WL[mat * 128 + (r15     ) * 4 + kg];
            bf16x8 al1 = WL[mat * 128 + (r15 + 16) * 4 + kg];
            #pragma unroll
            for (int sg2 = 0; sg2 < 2; ++sg2) {
                bf16x8 b = bf[m * 2 + sg2];
                f32x4 acc0 = {0.f, 0.f, 0.f, 0.f};
                f32x4 acc1 = {0.f, 0.f, 0.f, 0.f};
                acc0 = __builtin_amdgcn_mfma_f32_16x16x32_bf16(ah0, b, acc0, 0, 0, 0);
                acc0 = __builtin_amdgcn_mfma_f32_16x16x32_bf16(al0, b, acc0, 0, 0, 0);
                acc1 = __builtin_amdgcn_mfma_f32_16x16x32_bf16(ah1, b, acc1, 0, 0, 0);
                acc1 = __builtin_amdgcn_mfma_f32_16x16x32_bf16(al1, b, acc1, 0, 0, 0);
                if (grp < 3) {
                    // boundary: new site' = old_row*2+sigma, new k' = rb
                    #pragma unroll
                    for (int e = 0; e < 4; ++e) {
                        int k0 = kg * 4 + e;
                        int k1 = 16 + kg * 4 + e;
                        sbuf[(k0 * 2 + sg2) * 512 + (rb >> 3) * 128 +
                             r15 * 8 + (rb & 7)] = f2b(acc0[e]);
                        sbuf[(k1 * 2 + sg2) * 512 + (rb >> 3) * 128 +
                             r15 * 8 + (rb & 7)] = f2b(acc1[e]);
                    }
                } else {
                    // G3 is B-space: r = k*32 + class(rb); direct coalesced store
                    int col = col0 + sg2 * 16 + r15;
                    #pragma unroll
                    for (int e = 0; e < 4; ++e) {
                        int r0 = (kg * 4 + e) * 32 + rb;
                        int r1 = (16 + kg * 4 + e) * 32 + rb;
                        out[r0 * BATCH + col] = acc0[e];
                        out[r1 * BATCH + col] = acc1[e];
                    }
                }
            }
        }
        if (grp < 3) __syncthreads();    // writes done before next group's reads
    }
}

// ================= fallback: R15 path (proven 31.6us) =================
__device__ __host__ __forceinline__ int rowA(int sub, int i){ return (sub << 5) | i; }
__device__ __host__ __forceinline__ int rowB(int sub, int i){ return sub | (i << 5); }

__global__ void build_tab_kernel(const float* __restrict__ ang,
                                 float2* __restrict__ tab) {
    int idx = blockIdx.x * blockDim.x + threadIdx.x;
    if (idx >= TAB_ELEMS) return;
    int l = idx >> 9;
    int slot = idx & (NANG - 1);
    int sub = slot >> 4, p = slot & 15;
    int m10 = l % 10;
    int sp = m10;
    int SL = 1 << (m10 % 5);
    int i0 = 2 * (p / SL) * SL + p % SL;
    int r = (m10 >= 5) ? rowB(sub, i0) : rowA(sub, i0);
    int a = ((r >> (sp + 1)) << sp) | (r & ((1 << sp) - 1));
    float th = ang[l * NANG + a];
    float sv, cv;
    sincosf(th, &sv, &cv);
    tab[idx] = make_float2(cv, sv);
}

__device__ __forceinline__ void rotp(v2f& a, v2f& b, float cv, float sv) {
    v2f c = {cv, cv}, s = {sv, sv};
    v2f x0 = a, x1 = b;
    a = __builtin_elementwise_fma(c, x0, s * x1);
    b = __builtin_elementwise_fma(-s, x0, c * x1);
}

template<int SL>
__device__ __forceinline__ void layer_tab(v2f y[32],
                                          const float4* __restrict__ q4) {
    #pragma unroll
    for (int v = 0; v < 8; ++v) {
        float4 q = q4[v];
        int p0 = 2 * v, p1 = 2 * v + 1;
        int a0 = 2 * (p0 / SL) * SL + p0 % SL;
        int a1 = 2 * (p1 / SL) * SL + p1 % SL;
        rotp(y[a0], y[a0 + SL], q.x, q.y);
        rotp(y[a1], y[a1 + SL], q.z, q.w);
    }
}

template<int SL, bool PB, int SP>
__device__ __forceinline__ void layer_notab(v2f y[32],
                                            const float* __restrict__ angL,
                                            int sub) {
    #pragma unroll
    for (int p = 0; p < 16; ++p) {
        int i0 = 2 * (p / SL) * SL + p % SL;
        int r = PB ? rowB(sub, i0) : rowA(sub, i0);
        int a = ((r >> (SP + 1)) << SP) | (r & ((1 << SP) - 1));
        float th = angL[a];
        float sv, cv;
        __sincosf(th, &sv, &cv);
        rotp(y[i0], y[i0 + SL], cv, sv);
    }
}

template<bool USE_TAB>
__global__ __launch_bounds__(256) void butterfly_kernel(
        const float* __restrict__ X, const float* __restrict__ ang,
        const float2* __restrict__ tab, float* __restrict__ out) {
    __shared__ v2f lds[8 * 1024];
    int t = threadIdx.x;
    int c = t & 7;
    int sub = t >> 3;
    int bid = blockIdx.x;
    int L = ((bid & 7) << 6) | (bid >> 3);
    int col2 = (L << 3) + c;
    int xr = (c & 7) << 1;
    v2f* base = lds + (c << 10);

    v2f y[32];
    const v2f* Xp = reinterpret_cast<const v2f*>(X) + col2;
    #pragma unroll
    for (int i = 0; i < 32; ++i)
        y[i] = Xp[rowA(sub, i) * BATCH2];

    const float4* tf4 = reinterpret_cast<const float4*>(tab);
    if (USE_TAB) {
        layer_tab<1 >(y, tf4 + 0 * 256 + 8 * sub);
        layer_tab<2 >(y, tf4 + 1 * 256 + 8 * sub);
        layer_tab<4 >(y, tf4 + 2 * 256 + 8 * sub);
        layer_tab<8 >(y, tf4 + 3 * 256 + 8 * sub);
        layer_tab<16>(y, tf4 + 4 * 256 + 8 * sub);
    } else {
        layer_notab<1 ,false,0>(y, ang + 0 * NANG, sub);
        layer_notab<2 ,false,1>(y, ang + 1 * NANG, sub);
        layer_notab<4 ,false,2>(y, ang + 2 * NANG, sub);
        layer_notab<8 ,false,3>(y, ang + 3 * NANG, sub);
        layer_notab<16,false,4>(y, ang + 4 * NANG, sub);
    }
    #pragma unroll
    for (int u = 0; u < 16; ++u)
        *reinterpret_cast<float4*>(&base[((sub << 5) + 2 * u) ^ xr]) =
            make_float4(y[2*u].x, y[2*u].y, y[2*u+1].x, y[2*u+1].y);
    __syncthreads();
    #pragma unroll
    for (int i = 0; i < 32; ++i) y[i] = base[rowB(sub, i) ^ xr];

    if (USE_TAB) {
        layer_tab<1 >(y, tf4 + 5 * 256 + 8 * sub);
        layer_tab<2 >(y, tf4 + 6 * 256 + 8 * sub);
        layer_tab<4 >(y, tf4 + 7 * 256 + 8 * sub);
        layer_tab<8 >(y, tf4 + 8 * 256 + 8 * sub);
        layer_tab<16>(y, tf4 + 9 * 256 + 8 * sub);
    } else {
        layer_notab<1 ,true,5>(y, ang + 5 * NANG, sub);
        layer_notab<2 ,true,6>(y, ang + 6 * NANG, sub);
        layer_notab<4 ,true,7>(y, ang + 7 * NANG, sub);
        layer_notab<8 ,true,8>(y, ang + 8 * NANG, sub);
        layer_notab<16,true,9>(y, ang + 9 * NANG, sub);
    }
    __syncthreads();
    #pragma unroll
    for (int i = 0; i < 32; ++i) base[rowB(sub, i) ^ xr] = y[i];
    __syncthreads();
    #pragma unroll
    for (int u = 0; u < 16; ++u) {
        float4 v = *reinterpret_cast<const float4*>(&base[((sub << 5) + 2 * u) ^ xr]);
        y[2*u].x = v.x; y[2*u].y = v.y; y[2*u+1].x = v.z; y[2*u+1].y = v.w;
    }

    if (USE_TAB) {
        layer_tab<1 >(y, tf4 + 10 * 256 + 8 * sub);
        layer_tab<2 >(y, tf4 + 11 * 256 + 8 * sub);
        layer_tab<4 >(y, tf4 + 12 * 256 + 8 * sub);
        layer_tab<8 >(y, tf4 + 13 * 256 + 8 * sub);
        layer_tab<16>(y, tf4 + 14 * 256 + 8 * sub);
    } else {
        layer_notab<1 ,false,0>(y, ang + 10 * NANG, sub);
        layer_notab<2 ,false,1>(y, ang + 11 * NANG, sub);
        layer_notab<4 ,false,2>(y, ang + 12 * NANG, sub);
        layer_notab<8 ,false,3>(y, ang + 13 * NANG, sub);
        layer_notab<16,false,4>(y, ang + 14 * NANG, sub);
    }
    __syncthreads();
    #pragma unroll
    for (int u = 0; u < 16; ++u)
        *reinterpret_cast<float4*>(&base[((sub << 5) + 2 * u) ^ xr]) =
            make_float4(y[2*u].x, y[2*u].y, y[2*u+1].x, y[2*u+1].y);
    __syncthreads();
    #pragma unroll
    for (int i = 0; i < 32; ++i) y[i] = base[rowB(sub, i) ^ xr];

    if (USE_TAB) {
        layer_tab<1 >(y, tf4 + 15 * 256 + 8 * sub);
        layer_tab<2 >(y, tf4 + 16 * 256 + 8 * sub);
        layer_tab<4 >(y, tf4 + 17 * 256 + 8 * sub);
        layer_tab<8 >(y, tf4 + 18 * 256 + 8 * sub);
        layer_tab<16>(y, tf4 + 19 * 256 + 8 * sub);
    } else {
        layer_notab<1 ,true,5>(y, ang + 15 * NANG, sub);
        layer_notab<2 ,true,6>(y, ang + 16 * NANG, sub);
        layer_notab<4 ,true,7>(y, ang + 17 * NANG, sub);
        layer_notab<8 ,true,8>(y, ang + 18 * NANG, sub);
        layer_notab<16,true,9>(y, ang + 19 * NANG, sub);
    }

    v2f* Op = reinterpret_cast<v2f*>(out) + col2;
    #pragma unroll
    for (int i = 0; i < 32; ++i)
        Op[rowB(sub, i) * BATCH2] = y[i];
}

extern "C" void kernel_launch(void* const* d_in, const int* in_sizes, int n_in,
                              void* d_out, int out_size, void* d_ws, size_t ws_size,
                              hipStream_t stream) {
    (void)in_sizes; (void)n_in; (void)out_size;
    const float* X   = (const float*)d_in[0];
    const float* ang = (const float*)d_in[1];
    float* out = (float*)d_out;

    if (d_ws != nullptr && ws_size >= WS_MFMA_BYTES) {
        unsigned short* whi = (unsigned short*)d_ws;
        unsigned short* wlo = whi + 4 * 32 * 1024;
        build_w_kernel<<<64, 64, 0, stream>>>(ang, whi, wlo);
        mfma_kernel<<<256, 512, 0, stream>>>(X, whi, wlo, out);
    } else if (d_ws != nullptr && ws_size >= TAB_BYTES) {
        float2* tab = (float2*)d_ws;
        build_tab_kernel<<<(TAB_ELEMS + 255) / 256, 256, 0, stream>>>(ang, tab);
        butterfly_kernel<true><<<512, 256, 0, stream>>>(X, ang, tab, out);
    } else {
        butterfly_kernel<false><<<512, 256, 0, stream>>>(X, ang, nullptr, out);
    }
}